// Round 1
// baseline (1577.191 us; speedup 1.0000x reference)
//
#include <hip/hip_runtime.h>
#include <math.h>

#define D 64
#define R 5
#define EPT 4              // edges per thread
#define BLOCK 256
#define EPB (EPT * BLOCK)  // 1024 edges per block
#define DC 8               // d-chunk (rows of P)
#define FC 8               // f-chunk (cols of P)

__global__ __launch_bounds__(BLOCK, 2)
void bidecoder_kernel(const float* __restrict__ ufeat,
                      const float* __restrict__ ifeat,
                      const float* __restrict__ Ps,
                      const int* __restrict__ src,
                      const int* __restrict__ dst,
                      float* __restrict__ out, int E)
{
    const int tid = threadIdx.x;
    const int e0  = blockIdx.x * EPB + tid;

    int uoff[EPT], voff[EPT], eid[EPT];
    #pragma unroll
    for (int k = 0; k < EPT; ++k) {
        int e  = e0 + k * BLOCK;
        eid[k] = e;
        int es = (e < E) ? e : 0;          // clamp: harmless load for tail
        uoff[k] = src[es] * D;
        voff[k] = dst[es] * D;
    }

    float acc[EPT][R];
    #pragma unroll
    for (int k = 0; k < EPT; ++k)
        #pragma unroll
        for (int r = 0; r < R; ++r)
            acc[k][r] = 0.f;

    #pragma unroll 1
    for (int dc = 0; dc < D / DC; ++dc) {
        // us chunk: DC floats per edge, register-resident (compile-time indexed)
        float usr[EPT][DC];
        #pragma unroll
        for (int k = 0; k < EPT; ++k) {
            #pragma unroll
            for (int q = 0; q < DC / 4; ++q) {
                const float4 u4 = *reinterpret_cast<const float4*>(
                    ufeat + uoff[k] + dc * DC + q * 4);
                usr[k][q*4+0] = u4.x; usr[k][q*4+1] = u4.y;
                usr[k][q*4+2] = u4.z; usr[k][q*4+3] = u4.w;
            }
        }
        #pragma unroll 1
        for (int fc = 0; fc < D / FC; ++fc) {
            float vsr[EPT][FC];
            #pragma unroll
            for (int k = 0; k < EPT; ++k) {
                #pragma unroll
                for (int q = 0; q < FC / 4; ++q) {
                    const float4 v4 = *reinterpret_cast<const float4*>(
                        ifeat + voff[k] + fc * FC + q * 4);
                    vsr[k][q*4+0] = v4.x; vsr[k][q*4+1] = v4.y;
                    vsr[k][q*4+2] = v4.z; vsr[k][q*4+3] = v4.w;
                }
            }
            // P tile is wave-uniform -> scalar loads (s_load), no LDS needed
            #pragma unroll
            for (int d = 0; d < DC; ++d) {
                #pragma unroll
                for (int r = 0; r < R; ++r) {
                    const float* pr = Ps + ((size_t)(r * D) + dc * DC + d) * D + fc * FC;
                    const float4 pA = *reinterpret_cast<const float4*>(pr);
                    const float4 pB = *reinterpret_cast<const float4*>(pr + 4);
                    #pragma unroll
                    for (int k = 0; k < EPT; ++k) {
                        float t;
                        t = pA.x * vsr[k][0];
                        t = fmaf(pA.y, vsr[k][1], t);
                        t = fmaf(pA.z, vsr[k][2], t);
                        t = fmaf(pA.w, vsr[k][3], t);
                        t = fmaf(pB.x, vsr[k][4], t);
                        t = fmaf(pB.y, vsr[k][5], t);
                        t = fmaf(pB.z, vsr[k][6], t);
                        t = fmaf(pB.w, vsr[k][7], t);
                        acc[k][r] = fmaf(usr[k][d], t, acc[k][r]);
                    }
                }
            }
        }
    }

    // epilogue: softmax over R + expected rating
    #pragma unroll
    for (int k = 0; k < EPT; ++k) {
        if (eid[k] >= E) continue;
        float m = acc[k][0];
        #pragma unroll
        for (int r = 1; r < R; ++r) m = fmaxf(m, acc[k][r]);
        float s = 0.f, num = 0.f;
        #pragma unroll
        for (int r = 0; r < R; ++r) {
            const float p = expf(acc[k][r] - m);
            s += p;
            num = fmaf((float)(r + 1), p, num);
        }
        out[eid[k]] = num / s;
    }
}

extern "C" void kernel_launch(void* const* d_in, const int* in_sizes, int n_in,
                              void* d_out, int out_size, void* d_ws, size_t ws_size,
                              hipStream_t stream)
{
    const float* ufeat = (const float*)d_in[0];
    const float* ifeat = (const float*)d_in[1];
    const float* Ps    = (const float*)d_in[2];
    const int*   src   = (const int*)d_in[3];
    const int*   dst   = (const int*)d_in[4];
    float*       out   = (float*)d_out;
    const int E  = in_sizes[3];
    const int nb = (E + EPB - 1) / EPB;
    hipLaunchKernelGGL(bidecoder_kernel, dim3(nb), dim3(BLOCK), 0, stream,
                       ufeat, ifeat, Ps, src, dst, out, E);
}